// Round 12
// baseline (282.925 us; speedup 1.0000x reference)
//
#include <hip/hip_runtime.h>
#include <math.h>

#define N_NODES 20000
#define N_EDGES 100000
// dims: node 64, edge 32, heads 2, out 64 -> H*D = 128 everywhere

__device__ __forceinline__ float rl_f(float v, int l) {
    return __uint_as_float(__builtin_amdgcn_readlane(__float_as_uint(v), l));
}
__device__ __forceinline__ int rl_i(int v, int l) {
    return __builtin_amdgcn_readlane(v, l);
}
__device__ __forceinline__ float lrelu(float x) { return x > 0.f ? x : 0.2f * x; }

// ---------------------------------------------------------------------------
// scan_kernel — single-kernel CSR prefix sum.
// ---------------------------------------------------------------------------
__global__ __launch_bounds__(256) void scan_kernel(const int* __restrict__ cnt,
                                                   int* __restrict__ row_ptr) {
    __shared__ int sdata[256];
    __shared__ int swsum[4];
    const int tid = threadIdx.x;
    const int b = blockIdx.x;
    int idx = b * 256 + tid;
    int v = (idx < N_NODES) ? cnt[idx] : 0;
    sdata[tid] = v;
    int partial = 0;
    for (int i = tid; i < b * 256; i += 256) partial += cnt[i];
#pragma unroll
    for (int off = 32; off; off >>= 1) partial += __shfl_xor(partial, off);
    if ((tid & 63) == 0) swsum[tid >> 6] = partial;
    __syncthreads();
    const int boff = swsum[0] + swsum[1] + swsum[2] + swsum[3];
    for (int off = 1; off < 256; off <<= 1) {
        int t_ = (tid >= off) ? sdata[tid - off] : 0;
        __syncthreads();
        sdata[tid] += t_;
        __syncthreads();
    }
    if (idx < N_NODES) row_ptr[idx] = boff + sdata[tid] - v;
    if (b == 0 && tid == 0) row_ptr[N_NODES] = N_EDGES;
}

// ---------------------------------------------------------------------------
// setup_kernel — merged count + params (block-role partitioned):
//   blocks [0,391)         : CSR count (atomics) + pos
//   params blocks (b-391):
//     [0,4)   : P4 per layer (layer 2 via W_e2d chain)
//     ==4     : Q (edge-attention logit weights, 4 layers x 2 heads)
//     [5,53)  : pack weights into float4-interleaved wpack[4][3072]
//               (layer 2 Wn computed directly as W_e2d^T @ dWn, packed)
//     [53,...): layer-0 el/er over nodes
// ---------------------------------------------------------------------------
__global__ __launch_bounds__(256) void setup_kernel(
    const int* __restrict__ dst, int* __restrict__ cnt, int* __restrict__ pos,
    const float* __restrict__ Wn0, const float* __restrict__ al0, const float* __restrict__ ar0,
    const float* __restrict__ Wn1, const float* __restrict__ al1, const float* __restrict__ ar1,
    const float* __restrict__ dWn, const float* __restrict__ al2, const float* __restrict__ ar2,
    const float* __restrict__ Wn3, const float* __restrict__ al3, const float* __restrict__ ar3,
    const float* __restrict__ W_e2d,
    const float* __restrict__ We0, const float* __restrict__ ae0,
    const float* __restrict__ We1, const float* __restrict__ ae1,
    const float* __restrict__ We2, const float* __restrict__ ae2,
    const float* __restrict__ We3, const float* __restrict__ ae3,
    const float* __restrict__ X0,
    float* __restrict__ P4, float* __restrict__ Q, float4* __restrict__ Wpack,
    float2* __restrict__ EL2, float2* __restrict__ ER2) {
    __shared__ float praw[256];
    const int t = threadIdx.x;
    const int bb = blockIdx.x;

    if (bb < 391) {  // count
        int e = bb * 256 + t;
        if (e < N_EDGES) pos[e] = atomicAdd(&cnt[dst[e]], 1);
        return;
    }
    const int b = bb - 391;

    if (b < 4) {
        const int L = b;
        if (L != 2) {
            const float* Wn = (L == 0) ? Wn0 : (L == 1) ? Wn1 : Wn3;
            const float* al = (L == 0) ? al0 : (L == 1) ? al1 : al3;
            const float* ar = (L == 0) ? ar0 : (L == 1) ? ar1 : ar3;
            const int k = t >> 2, o = t & 3;
            const float* a = (o & 2) ? ar : al;
            const int h = o & 1;
            float acc = 0.f;
#pragma unroll 8
            for (int d = 0; d < 64; d++) acc = fmaf(Wn[k * 128 + h * 64 + d], a[h * 64 + d], acc);
            P4[L * 256 + t] = acc;
        } else {
            {
                const int i = t >> 2, o = t & 3;
                const float* a = (o & 2) ? ar2 : al2;
                const int h = o & 1;
                float acc = 0.f;
#pragma unroll 8
                for (int d = 0; d < 64; d++) acc = fmaf(dWn[i * 128 + h * 64 + d], a[h * 64 + d], acc);
                praw[t] = acc;
            }
            __syncthreads();
            const int j = t >> 2, o = t & 3;
            float acc = 0.f;
#pragma unroll 8
            for (int i = 0; i < 64; i++) acc = fmaf(W_e2d[i * 64 + j], praw[i * 4 + o], acc);
            P4[2 * 256 + t] = acc;
        }
    } else if (b == 4) {
        const int k = t >> 3, o = t & 7, L = o >> 1, h = o & 1;
        const float* We = (L == 0) ? We0 : (L == 1) ? We1 : (L == 2) ? We2 : We3;
        const float* ae = (L == 0) ? ae0 : (L == 1) ? ae1 : (L == 2) ? ae2 : ae3;
        float acc = 0.f;
#pragma unroll 8
        for (int d = 0; d < 64; d++) acc = fmaf(We[k * 128 + h * 64 + d], ae[h * 64 + d], acc);
        Q[t] = acc;
    } else if (b < 53) {
        // pack: idx in [0,12288); layer L gets 3072 float4 (2048 Wn + 1024 We)
        const int idx = (b - 5) * 256 + t;
        const int L = idx / 3072;
        const int sub = idx - L * 3072;
        if (sub < 2048) {
            const int k2 = sub >> 6, l = sub & 63;
            if (L != 2) {
                const float* Wn = (L == 0) ? Wn0 : (L == 1) ? Wn1 : Wn3;
                Wpack[idx] = make_float4(Wn[(2 * k2) * 128 + l], Wn[(2 * k2) * 128 + 64 + l],
                                         Wn[(2 * k2 + 1) * 128 + l], Wn[(2 * k2 + 1) * 128 + 64 + l]);
            } else {
                // wcomb[k][c] = sum_i W_e2d[i*64+k] * dWn[i*128+c], packed directly
                float a0 = 0.f, a1 = 0.f, a2 = 0.f, a3 = 0.f;
#pragma unroll 4
                for (int i = 0; i < 64; i++) {
                    float wa = W_e2d[i * 64 + 2 * k2], wb = W_e2d[i * 64 + 2 * k2 + 1];
                    float da = dWn[i * 128 + l], db = dWn[i * 128 + 64 + l];
                    a0 = fmaf(wa, da, a0);
                    a1 = fmaf(wa, db, a1);
                    a2 = fmaf(wb, da, a2);
                    a3 = fmaf(wb, db, a3);
                }
                Wpack[idx] = make_float4(a0, a1, a2, a3);
            }
        } else {
            const int s2 = sub - 2048;
            const int k2 = s2 >> 6, l = s2 & 63;
            const float* We = (L == 0) ? We0 : (L == 1) ? We1 : (L == 2) ? We2 : We3;
            Wpack[idx] = make_float4(We[(2 * k2) * 128 + l], We[(2 * k2) * 128 + 64 + l],
                                     We[(2 * k2 + 1) * 128 + l], We[(2 * k2 + 1) * 128 + 64 + l]);
        }
    } else {
        {
            const int k = t >> 2, o = t & 3;
            const float* a = (o & 2) ? ar0 : al0;
            const int h = o & 1;
            float acc = 0.f;
#pragma unroll 8
            for (int d = 0; d < 64; d++) acc = fmaf(Wn0[k * 128 + h * 64 + d], a[h * 64 + d], acc);
            praw[t] = acc;
        }
        __syncthreads();
        const int lane = t & 63;
        const int wave = t >> 6;
        const float px = praw[lane * 4 + 0], py = praw[lane * 4 + 1];
        const float pz = praw[lane * 4 + 2], pw = praw[lane * 4 + 3];
        const int nb = (int)gridDim.x - 444;  // blocks doing el/er
        for (int node = (b - 53) * 4 + wave; node < N_NODES; node += nb * 4) {
            float xv = X0[node * 64 + lane];
            float e0 = xv * px, e1 = xv * py, f0 = xv * pz, f1 = xv * pw;
#pragma unroll
            for (int off = 32; off; off >>= 1) {
                e0 += __shfl_xor(e0, off);
                e1 += __shfl_xor(e1, off);
                f0 += __shfl_xor(f0, off);
                f1 += __shfl_xor(f1, off);
            }
            if (lane == 0) {
                EL2[node] = make_float2(e0, e1);
                ER2[node] = make_float2(f0, f1);
            }
        }
    }
}

// ---------------------------------------------------------------------------
// prep: one pass over Efeat -> e_csr, src_csr, EE_csr (4 layers x 2 heads)
// ---------------------------------------------------------------------------
__global__ __launch_bounds__(256) void prep_kernel(const float* __restrict__ Efeat,
                                                   const int* __restrict__ src,
                                                   const int* __restrict__ dst,
                                                   const int* __restrict__ pos,
                                                   const int* __restrict__ row_ptr,
                                                   const float* __restrict__ Q,
                                                   float* __restrict__ E_csr,
                                                   int* __restrict__ src_csr,
                                                   float* __restrict__ EE_csr) {
    __shared__ float QS[256];
    __shared__ float ES[32][33];
    __shared__ int JS[32];
    const int tid = threadIdx.x;
    QS[tid] = Q[tid];
    const int e0 = blockIdx.x * 32;
    const int el_ = tid >> 3, quad = tid & 7;
    float4 v = ((const float4*)Efeat)[(size_t)(e0 + el_) * 8 + quad];
    ES[el_][quad * 4 + 0] = v.x;
    ES[el_][quad * 4 + 1] = v.y;
    ES[el_][quad * 4 + 2] = v.z;
    ES[el_][quad * 4 + 3] = v.w;
    if (tid < 32) {
        int e = e0 + tid;
        int j = row_ptr[dst[e]] + pos[e];
        JS[tid] = j;
        src_csr[j] = src[e];
    }
    __syncthreads();
    const int j = JS[el_];
    ((float4*)E_csr)[(size_t)j * 8 + quad] = v;
    const int o = quad;
    float acc = 0.f;
#pragma unroll
    for (int k = 0; k < 32; k++) acc = fmaf(ES[el_][k], QS[k * 8 + o], acc);
    EE_csr[(size_t)(o >> 1) * 2 * N_EDGES + (size_t)j * 2 + (o & 1)] = acc;
}

// ---------------------------------------------------------------------------
// gather_one — full per-node gather (deg 0 / <=64 / fallback). Used for the
// rare non-fast-path nodes in the dual-node layer kernel.
// ---------------------------------------------------------------------------
__device__ __forceinline__ void gather_one(
    int beg, int end, float2 er,
    const float* __restrict__ X, const float* __restrict__ E_csr,
    const int* __restrict__ src_csr, const float2* __restrict__ ELi,
    const float2* __restrict__ EE_L,
    int lane, int half, int hl,
    float& ax0, float& ax1, float& aeh) {
    ax0 = 0.f; ax1 = 0.f; aeh = 0.f;
    const int deg = end - beg;
    if (deg == 0) return;
    float l0 = 0.f, l1 = 0.f, aX0 = 0.f, aX1 = 0.f, aE = 0.f;
    if (deg <= 64) {
        int sn = 0;
        float w0 = 0.f, w1 = 0.f;
        if (lane < deg) {
            sn = src_csr[beg + lane];
            float2 ee = EE_L[beg + lane];
            float2 el = ELi[sn];
            w0 = __expf(lrelu(el.x + er.x + ee.x));
            w1 = __expf(lrelu(el.y + er.y + ee.y));
        }
        l0 = w0; l1 = w1;
#pragma unroll
        for (int off = 32; off; off >>= 1) {
            l0 += __shfl_xor(l0, off);
            l1 += __shfl_xor(l1, off);
        }
        const int dm1 = deg - 1;
        {
            float xs[8], es[8];
#pragma unroll
            for (int t = 0; t < 8; t++) {
                int ct = t < dm1 ? t : dm1;
                int st = rl_i(sn, ct);
                xs[t] = X[st * 64 + lane];
                es[t] = E_csr[(size_t)(beg + ct) * 32 + hl];
            }
#pragma unroll
            for (int t = 0; t < 8; t++) {
                float w0t = rl_f(w0, t);
                float w1t = rl_f(w1, t);
                aX0 = fmaf(w0t, xs[t], aX0);
                aX1 = fmaf(w1t, xs[t], aX1);
                aE = fmaf(half ? w1t : w0t, es[t], aE);
            }
        }
        int t = 8;
        for (; t + 4 <= deg; t += 4) {
            int s0 = rl_i(sn, t), s1 = rl_i(sn, t + 1);
            int s2 = rl_i(sn, t + 2), s3 = rl_i(sn, t + 3);
            float x0 = X[s0 * 64 + lane];
            float x1 = X[s1 * 64 + lane];
            float x2 = X[s2 * 64 + lane];
            float x3 = X[s3 * 64 + lane];
            const float* Eb = E_csr + (size_t)(beg + t) * 32 + hl;
            float e0 = Eb[0], e1 = Eb[32], e2 = Eb[64], e3 = Eb[96];
            float w00 = rl_f(w0, t), w01 = rl_f(w0, t + 1);
            float w02 = rl_f(w0, t + 2), w03 = rl_f(w0, t + 3);
            float w10 = rl_f(w1, t), w11 = rl_f(w1, t + 1);
            float w12 = rl_f(w1, t + 2), w13 = rl_f(w1, t + 3);
            aX0 = fmaf(w00, x0, aX0); aX1 = fmaf(w10, x0, aX1);
            aX0 = fmaf(w01, x1, aX0); aX1 = fmaf(w11, x1, aX1);
            aX0 = fmaf(w02, x2, aX0); aX1 = fmaf(w12, x2, aX1);
            aX0 = fmaf(w03, x3, aX0); aX1 = fmaf(w13, x3, aX1);
            aE = fmaf(half ? w10 : w00, e0, aE);
            aE = fmaf(half ? w11 : w01, e1, aE);
            aE = fmaf(half ? w12 : w02, e2, aE);
            aE = fmaf(half ? w13 : w03, e3, aE);
        }
        for (; t < deg; t++) {
            int st = rl_i(sn, t);
            float w0t = rl_f(w0, t), w1t = rl_f(w1, t);
            float xv = X[st * 64 + lane];
            float ev = E_csr[(size_t)(beg + t) * 32 + hl];
            aX0 = fmaf(w0t, xv, aX0);
            aX1 = fmaf(w1t, xv, aX1);
            aE = fmaf(half ? w1t : w0t, ev, aE);
        }
    } else {
        for (int c = beg; c < end; c += 64) {
            int jj = c + lane;
            int sn_ = 0;
            float w0c = 0.f, w1c = 0.f;
            if (jj < end) {
                sn_ = src_csr[jj];
                float2 ee = EE_L[jj];
                float2 el = ELi[sn_];
                w0c = __expf(lrelu(el.x + er.x + ee.x));
                w1c = __expf(lrelu(el.y + er.y + ee.y));
            }
            float s0_ = w0c, s1_ = w1c;
#pragma unroll
            for (int off = 32; off; off >>= 1) {
                s0_ += __shfl_xor(s0_, off);
                s1_ += __shfl_xor(s1_, off);
            }
            l0 += s0_;
            l1 += s1_;
            int nch = (end - c) < 64 ? (end - c) : 64;
            for (int t = 0; t < nch; t++) {
                int st = rl_i(sn_, t);
                float w0t = rl_f(w0c, t), w1t = rl_f(w1c, t);
                float xv = X[st * 64 + lane];
                float ev = E_csr[(size_t)(c + t) * 32 + hl];
                aX0 = fmaf(w0t, xv, aX0);
                aX1 = fmaf(w1t, xv, aX1);
                aE = fmaf(half ? w1t : w0t, ev, aE);
            }
        }
    }
    const float inv0 = l0 > 0.f ? 1.f / l0 : 0.f;
    const float inv1 = l1 > 0.f ? 1.f / l1 : 0.f;
    ax0 = aX0 * inv0;
    ax1 = aX1 * inv1;
    aeh = aE * (half ? inv1 : inv0);
}

// ---------------------------------------------------------------------------
// layer_kernel — FUSED gather + matmul-epilogue + next-layer el/er.
// ONE-SHOT, TWO NODES PER WAVE (R9 structure: 269.8 us best; R11 showed
// 4-node is neutral-to-worse -> ILP saturated at 2). NEW in R12: NO LDS
// weight staging and NO BARRIER. The Wn/We packs (48 KB, shared by all
// 2500 blocks) are read straight from global in the epilogue — they are
// L1/L2-hot after the first blocks per CU, and the lane-indexed reads are
// coalesced 1KB/instr (exactly how the We-pack has worked since R4).
// This removes (a) 32KB x 2500 blocks of redundant LDS-fill traffic,
// (b) the block-start __syncthreads (waves start gathering immediately),
// (c) drops LDS to 6 KB (wave-private BC4/AE2 slabs only) — which also
// probes whether LDS accounting was the mysterious ~2-wg/CU residency cap.
// VGPR watch: must stay <= 256 (spill = 100+ MB FETCH -> revert).
// ---------------------------------------------------------------------------
__global__ __launch_bounds__(256) void layer_kernel(
    const float* __restrict__ X,
    const float2* __restrict__ ELi, const float2* __restrict__ ERi,
    const float* __restrict__ E_csr, const int* __restrict__ src_csr,
    const int* __restrict__ row_ptr, const float2* __restrict__ EE_L,
    const float4* __restrict__ Wp, const float* __restrict__ bias,
    const float* __restrict__ P4next, const int has_next,
    float* __restrict__ OUT,
    float2* __restrict__ ELo, float2* __restrict__ ERo) {
    __shared__ float4 BC4[256];   //  4 KB: per-wave broadcast slab (w's, then ax's)
    __shared__ float2 AE2[256];   //  2 KB: per-wave (aeha, aehb)
    const int tid = threadIdx.x;
    const int lane = tid & 63;
    const int wave = tid >> 6;
    const int half = lane >> 5, hl = lane & 31;
    const int wb = wave * 64;     // wave-private slab base

    // ---- per-wave CSR bounds + er: dependent chain starts immediately ----
    const int n0 = blockIdx.x * 8 + wave * 2;  // 2500*8 == 20000 exactly
    const int n1 = n0 + 1;
    const int beg0 = row_ptr[n0];
    const int beg1 = row_ptr[n1];   // == end0
    const int end1 = row_ptr[n1 + 1];
    const float2 er0 = ERi[n0];
    const float2 er1 = ERi[n1];
    const float bb0 = bias[lane], bb1 = bias[64 + lane];
    const float4 p = has_next ? ((const float4*)P4next)[lane] : make_float4(0.f, 0.f, 0.f, 0.f);
    const float4* __restrict__ WnG = Wp;         // 32 KB, L1/L2-hot
    const float4* __restrict__ WeG = Wp + 2048;  // 16 KB, L1-resident

    const int end0 = beg1;
    const int deg0 = end0 - beg0;
    const int deg1 = end1 - beg1;

    float ax0a = 0.f, ax1a = 0.f, aeha = 0.f;
    float ax0b = 0.f, ax1b = 0.f, aehb = 0.f;

    if (deg0 > 0 && deg0 <= 64 && deg1 > 0 && deg1 <= 64) {
        // ---- dual fast path: both chains interleaved ----
        int sn0 = 0, sn1 = 0;
        float w0a = 0.f, w1a = 0.f, w0b = 0.f, w1b = 0.f;
        if (lane < deg0) {
            sn0 = src_csr[beg0 + lane];
            float2 ee = EE_L[beg0 + lane];
            float2 el = ELi[sn0];
            w0a = __expf(lrelu(el.x + er0.x + ee.x));
            w1a = __expf(lrelu(el.y + er0.y + ee.y));
        }
        if (lane < deg1) {
            sn1 = src_csr[beg1 + lane];
            float2 ee = EE_L[beg1 + lane];
            float2 el = ELi[sn1];
            w0b = __expf(lrelu(el.x + er1.x + ee.x));
            w1b = __expf(lrelu(el.y + er1.y + ee.y));
        }
        // publish weights for LDS broadcast (lanes >= deg hold 0)
        BC4[wb + lane] = make_float4(w0a, w1a, w0b, w1b);
        float l0a = w0a, l1a = w1a, l0b = w0b, l1b = w1b;
#pragma unroll
        for (int off = 32; off; off >>= 1) {
            l0a += __shfl_xor(l0a, off);
            l1a += __shfl_xor(l1a, off);
            l0b += __shfl_xor(l0b, off);
            l1b += __shfl_xor(l1b, off);
        }
        float aX0a = 0.f, aX1a = 0.f, aEa = 0.f;
        float aX0b = 0.f, aX1b = 0.f, aEb = 0.f;
        const int dma = deg0 - 1, dmb = deg1 - 1;
        {
            // 32 loads in flight across both nodes
            float xs0[8], es0[8], xs1[8], es1[8];
#pragma unroll
            for (int t = 0; t < 8; t++) {
                int c0 = t < dma ? t : dma;
                int c1 = t < dmb ? t : dmb;
                int s0 = rl_i(sn0, c0);
                int s1 = rl_i(sn1, c1);
                xs0[t] = X[s0 * 64 + lane];
                es0[t] = E_csr[(size_t)(beg0 + c0) * 32 + hl];
                xs1[t] = X[s1 * 64 + lane];
                es1[t] = E_csr[(size_t)(beg1 + c1) * 32 + hl];
            }
#pragma unroll
            for (int t = 0; t < 8; t++) {
                float4 wt = BC4[wb + t];  // broadcast: 4 scalars, 1 LDS op
                aX0a = fmaf(wt.x, xs0[t], aX0a);
                aX1a = fmaf(wt.y, xs0[t], aX1a);
                aEa = fmaf(half ? wt.y : wt.x, es0[t], aEa);
                aX0b = fmaf(wt.z, xs1[t], aX0b);
                aX1b = fmaf(wt.w, xs1[t], aX1b);
                aEb = fmaf(half ? wt.w : wt.z, es1[t], aEb);
            }
        }
        // remainders (deg > 8): per node, x4 then singles
        int t = 8;
        for (; t + 4 <= deg0; t += 4) {
            int s0 = rl_i(sn0, t), s1 = rl_i(sn0, t + 1);
            int s2 = rl_i(sn0, t + 2), s3 = rl_i(sn0, t + 3);
            float x0 = X[s0 * 64 + lane];
            float x1 = X[s1 * 64 + lane];
            float x2 = X[s2 * 64 + lane];
            float x3 = X[s3 * 64 + lane];
            const float* Eb = E_csr + (size_t)(beg0 + t) * 32 + hl;
            float e0 = Eb[0], e1 = Eb[32], e2 = Eb[64], e3 = Eb[96];
            float4 wt0 = BC4[wb + t], wt1 = BC4[wb + t + 1];
            float4 wt2 = BC4[wb + t + 2], wt3 = BC4[wb + t + 3];
            aX0a = fmaf(wt0.x, x0, aX0a); aX1a = fmaf(wt0.y, x0, aX1a);
            aX0a = fmaf(wt1.x, x1, aX0a); aX1a = fmaf(wt1.y, x1, aX1a);
            aX0a = fmaf(wt2.x, x2, aX0a); aX1a = fmaf(wt2.y, x2, aX1a);
            aX0a = fmaf(wt3.x, x3, aX0a); aX1a = fmaf(wt3.y, x3, aX1a);
            aEa = fmaf(half ? wt0.y : wt0.x, e0, aEa);
            aEa = fmaf(half ? wt1.y : wt1.x, e1, aEa);
            aEa = fmaf(half ? wt2.y : wt2.x, e2, aEa);
            aEa = fmaf(half ? wt3.y : wt3.x, e3, aEa);
        }
        for (; t < deg0; t++) {
            int st = rl_i(sn0, t);
            float4 wt = BC4[wb + t];
            float xv = X[st * 64 + lane];
            float ev = E_csr[(size_t)(beg0 + t) * 32 + hl];
            aX0a = fmaf(wt.x, xv, aX0a);
            aX1a = fmaf(wt.y, xv, aX1a);
            aEa = fmaf(half ? wt.y : wt.x, ev, aEa);
        }
        t = 8;
        for (; t + 4 <= deg1; t += 4) {
            int s0 = rl_i(sn1, t), s1 = rl_i(sn1, t + 1);
            int s2 = rl_i(sn1, t + 2), s3 = rl_i(sn1, t + 3);
            float x0 = X[s0 * 64 + lane];
            float x1 = X[s1 * 64 + lane];
            float x2 = X[s2 * 64 + lane];
            float x3 = X[s3 * 64 + lane];
            const float* Eb = E_csr + (size_t)(beg1 + t) * 32 + hl;
            float e0 = Eb[0], e1 = Eb[32], e2 = Eb[64], e3 = Eb[96];
            float4 wt0 = BC4[wb + t], wt1 = BC4[wb + t + 1];
            float4 wt2 = BC4[wb + t + 2], wt3 = BC4[wb + t + 3];
            aX0b = fmaf(wt0.z, x0, aX0b); aX1b = fmaf(wt0.w, x0, aX1b);
            aX0b = fmaf(wt1.z, x1, aX0b); aX1b = fmaf(wt1.w, x1, aX1b);
            aX0b = fmaf(wt2.z, x2, aX0b); aX1b = fmaf(wt2.w, x2, aX1b);
            aX0b = fmaf(wt3.z, x3, aX0b); aX1b = fmaf(wt3.w, x3, aX1b);
            aEb = fmaf(half ? wt0.w : wt0.z, e0, aEb);
            aEb = fmaf(half ? wt1.w : wt1.z, e1, aEb);
            aEb = fmaf(half ? wt2.w : wt2.z, e2, aEb);
            aEb = fmaf(half ? wt3.w : wt3.z, e3, aEb);
        }
        for (; t < deg1; t++) {
            int st = rl_i(sn1, t);
            float4 wt = BC4[wb + t];
            float xv = X[st * 64 + lane];
            float ev = E_csr[(size_t)(beg1 + t) * 32 + hl];
            aX0b = fmaf(wt.z, xv, aX0b);
            aX1b = fmaf(wt.w, xv, aX1b);
            aEb = fmaf(half ? wt.w : wt.z, ev, aEb);
        }
        const float i0a = l0a > 0.f ? 1.f / l0a : 0.f;
        const float i1a = l1a > 0.f ? 1.f / l1a : 0.f;
        const float i0b = l0b > 0.f ? 1.f / l0b : 0.f;
        const float i1b = l1b > 0.f ? 1.f / l1b : 0.f;
        ax0a = aX0a * i0a; ax1a = aX1a * i1a; aeha = aEa * (half ? i1a : i0a);
        ax0b = aX0b * i0b; ax1b = aX1b * i1b; aehb = aEb * (half ? i1b : i0b);
    } else {
        // rare path (deg==0 or deg>64 on either node): sequential full gather
        gather_one(beg0, end0, er0, X, E_csr, src_csr, ELi, EE_L, lane, half, hl,
                   ax0a, ax1a, aeha);
        gather_one(beg1, end1, er1, X, E_csr, src_csr, ELi, EE_L, lane, half, hl,
                   ax0b, ax1b, aehb);
    }

    // --- publish aggregates for the broadcast epilogue (reuse BC4 slab) ---
    BC4[wb + lane] = make_float4(ax0a, ax1a, ax0b, ax1b);
    AE2[wb + lane] = make_float2(aeha, aehb);

    // --- fused 2-node epilogue: Wn/We from global (L1-hot), aggregates via
    //     LDS broadcast ---
    float r0a = 0.f, r1a = 0.f, r0b = 0.f, r1b = 0.f;
#pragma unroll
    for (int k2 = 0; k2 < 32; k2++) {
        float4 w4 = WnG[k2 * 64 + lane];
        float4 a0 = BC4[wb + 2 * k2];      // (ax0a,ax1a,ax0b,ax1b)[2k2]
        float4 a1 = BC4[wb + 2 * k2 + 1];  // same at 2k2+1
        r0a = fmaf(a0.x, w4.x, r0a); r1a = fmaf(a0.y, w4.y, r1a);
        r0a = fmaf(a1.x, w4.z, r0a); r1a = fmaf(a1.y, w4.w, r1a);
        r0b = fmaf(a0.z, w4.x, r0b); r1b = fmaf(a0.w, w4.y, r1b);
        r0b = fmaf(a1.z, w4.z, r0b); r1b = fmaf(a1.w, w4.w, r1b);
    }
#pragma unroll
    for (int k2 = 0; k2 < 16; k2++) {
        float4 w4 = WeG[k2 * 64 + lane];
        float2 e0 = AE2[wb + 2 * k2];
        float2 e1 = AE2[wb + 2 * k2 + 1];
        float2 e2 = AE2[wb + 32 + 2 * k2];
        float2 e3 = AE2[wb + 32 + 2 * k2 + 1];
        r0a = fmaf(e0.x, w4.x, r0a); r1a = fmaf(e2.x, w4.y, r1a);
        r0a = fmaf(e1.x, w4.z, r0a); r1a = fmaf(e3.x, w4.w, r1a);
        r0b = fmaf(e0.y, w4.x, r0b); r1b = fmaf(e2.y, w4.y, r1b);
        r0b = fmaf(e1.y, w4.z, r0b); r1b = fmaf(e3.y, w4.w, r1b);
    }
    const float outa = 0.5f * (r0a + bb0 + r1a + bb1);
    const float outb = 0.5f * (r0b + bb0 + r1b + bb1);
    OUT[n0 * 64 + lane] = outa;
    OUT[n1 * 64 + lane] = outb;
    if (has_next) {
        float e0a = outa * p.x, e1a = outa * p.y, f0a = outa * p.z, f1a = outa * p.w;
        float e0b = outb * p.x, e1b = outb * p.y, f0b = outb * p.z, f1b = outb * p.w;
#pragma unroll
        for (int off = 32; off; off >>= 1) {
            e0a += __shfl_xor(e0a, off); e1a += __shfl_xor(e1a, off);
            f0a += __shfl_xor(f0a, off); f1a += __shfl_xor(f1a, off);
            e0b += __shfl_xor(e0b, off); e1b += __shfl_xor(e1b, off);
            f0b += __shfl_xor(f0b, off); f1b += __shfl_xor(f1b, off);
        }
        if (lane == 0) {
            ELo[n0] = make_float2(e0a, e1a);
            ERo[n0] = make_float2(f0a, f1a);
            ELo[n1] = make_float2(e0b, e1b);
            ERo[n1] = make_float2(f0b, f1b);
        }
    }
}

// ---------------------------------------------------------------------------
extern "C" void kernel_launch(void* const* d_in, const int* in_sizes, int n_in,
                              void* d_out, int out_size, void* d_ws, size_t ws_size,
                              hipStream_t stream) {
    const float* x = (const float*)d_in[0];
    const float* e = (const float*)d_in[1];
    const int* src = (const int*)d_in[2];
    const int* dst = (const int*)d_in[3];

    // Only the LAST snapshot contributes to the output (decoded[-1]).
    const float* x1 = x + (size_t)1 * N_NODES * 64;
    const float* e1 = e + (size_t)1 * N_EDGES * 32;
    const int* src1 = src + N_EDGES;
    const int* dst1 = dst + N_EDGES;

    int we2d_idx, dec0_b, dec1_b;
    if (in_sizes[16] == 64 * 64 && in_sizes[17] == 64 * 128) {
        we2d_idx = 16; dec0_b = 17; dec1_b = 23;
    } else {
        dec0_b = 16; dec1_b = 22; we2d_idx = 28;
    }
    auto P = [&](int i) { return (const float*)d_in[i]; };

    // workspace layout (bytes)
    char* ws = (char*)d_ws;
    int* cnt      = (int*)(ws + 0);          //     80,000
    int* row_ptr  = (int*)(ws + 80000);      //     80,004
    int* pos      = (int*)(ws + 160064);     //    400,000
    float* q      = (float*)(ws + 560576);   //      1,024
    int* src_csr  = (int*)(ws + 561600);     //    400,000
    float* e_csr  = (float*)(ws + 961600);   // 12,800,000
    float* ee_csr = (float*)(ws + 13761600); //  3,200,000
    float* p4_all = (float*)(ws + 16961600); //      4,096
    float* elA    = (float*)(ws + 16965696); //    160,000
    float* erA    = (float*)(ws + 17125696); //    160,000
    float* elB    = (float*)(ws + 17285696); //    160,000
    float* erB    = (float*)(ws + 17445696); //    160,000
    float* h0     = (float*)(ws + 17605696); //  5,120,000
    float* h1     = (float*)(ws + 22725696); //  5,120,000
    float4* wpack = (float4*)(ws + 27845696);//    196,608
    // total ~28.1 MB

    hipMemsetAsync(cnt, 0, N_NODES * sizeof(int), stream);

    // merged count + params: 391 count blocks + 512 param blocks
    setup_kernel<<<903, 256, 0, stream>>>(
        dst1, cnt, pos,
        P(4), P(6), P(7),
        P(10), P(12), P(13),
        P(dec0_b + 0), P(dec0_b + 2), P(dec0_b + 3),
        P(dec1_b + 0), P(dec1_b + 2), P(dec1_b + 3),
        P(we2d_idx),
        P(5), P(8), P(11), P(14),
        P(dec0_b + 1), P(dec0_b + 4), P(dec1_b + 1), P(dec1_b + 4),
        x1,
        p4_all, q, wpack, (float2*)elA, (float2*)erA);

    const int SB = (N_NODES + 255) / 256;  // 79
    scan_kernel<<<SB, 256, 0, stream>>>(cnt, row_ptr);

    prep_kernel<<<N_EDGES / 32, 256, 0, stream>>>(e1, src1, dst1, pos, row_ptr, q,
                                                  e_csr, src_csr, ee_csr);

    // fused layer kernels: ONE-SHOT, 2500 blocks x 256 thr, 2 nodes/wave,
    // no LDS weight staging, no barrier
    const int NB_L = N_NODES / 8;  // 2500
    auto run = [&](const float* Xin, int L, const float* bias_,
                   const float* elI, const float* erI,
                   float* Out, float* elO, float* erO, int hn) {
        layer_kernel<<<NB_L, 256, 0, stream>>>(
            Xin, (const float2*)elI, (const float2*)erI,
            e_csr, src_csr, row_ptr,
            (const float2*)ee_csr + (size_t)L * N_EDGES,
            wpack + (size_t)L * 3072, bias_,
            p4_all + (L + 1) * 256, hn,
            Out, (float2*)elO, (float2*)erO);
    };

    run(x1, 0, P(9),           elA, erA, h0, elB, erB, 1);
    run(h0, 1, P(15),          elB, erB, h1, elA, erA, 1);
    run(h1, 2, P(dec0_b + 5),  elA, erA, h0, elB, erB, 1);
    run(h0, 3, P(dec1_b + 5),  elB, erB, (float*)d_out, elA, erA, 0);
}

// Round 13
// 265.662 us; speedup vs baseline: 1.0650x; 1.0650x over previous
//
#include <hip/hip_runtime.h>
#include <math.h>

#define N_NODES 20000
#define N_EDGES 100000
// dims: node 64, edge 32, heads 2, out 64 -> H*D = 128 everywhere

__device__ __forceinline__ float rl_f(float v, int l) {
    return __uint_as_float(__builtin_amdgcn_readlane(__float_as_uint(v), l));
}
__device__ __forceinline__ int rl_i(int v, int l) {
    return __builtin_amdgcn_readlane(v, l);
}
__device__ __forceinline__ float lrelu(float x) { return x > 0.f ? x : 0.2f * x; }

// ---------------------------------------------------------------------------
// scan_kernel — single-kernel CSR prefix sum.
// ---------------------------------------------------------------------------
__global__ __launch_bounds__(256) void scan_kernel(const int* __restrict__ cnt,
                                                   int* __restrict__ row_ptr) {
    __shared__ int sdata[256];
    __shared__ int swsum[4];
    const int tid = threadIdx.x;
    const int b = blockIdx.x;
    int idx = b * 256 + tid;
    int v = (idx < N_NODES) ? cnt[idx] : 0;
    sdata[tid] = v;
    int partial = 0;
    for (int i = tid; i < b * 256; i += 256) partial += cnt[i];
#pragma unroll
    for (int off = 32; off; off >>= 1) partial += __shfl_xor(partial, off);
    if ((tid & 63) == 0) swsum[tid >> 6] = partial;
    __syncthreads();
    const int boff = swsum[0] + swsum[1] + swsum[2] + swsum[3];
    for (int off = 1; off < 256; off <<= 1) {
        int t_ = (tid >= off) ? sdata[tid - off] : 0;
        __syncthreads();
        sdata[tid] += t_;
        __syncthreads();
    }
    if (idx < N_NODES) row_ptr[idx] = boff + sdata[tid] - v;
    if (b == 0 && tid == 0) row_ptr[N_NODES] = N_EDGES;
}

// ---------------------------------------------------------------------------
// setup_kernel — merged count + params (block-role partitioned):
//   blocks [0,391)         : CSR count (atomics) + pos
//   params blocks (b-391):
//     [0,4)   : P4 per layer (layer 2 via W_e2d chain)
//     ==4     : Q (edge-attention logit weights, 4 layers x 2 heads)
//     [5,53)  : pack weights into float4-interleaved wpack[4][3072]
//               (layer 2 Wn computed directly as W_e2d^T @ dWn, packed)
//     [53,...): layer-0 el/er over nodes
// ---------------------------------------------------------------------------
__global__ __launch_bounds__(256) void setup_kernel(
    const int* __restrict__ dst, int* __restrict__ cnt, int* __restrict__ pos,
    const float* __restrict__ Wn0, const float* __restrict__ al0, const float* __restrict__ ar0,
    const float* __restrict__ Wn1, const float* __restrict__ al1, const float* __restrict__ ar1,
    const float* __restrict__ dWn, const float* __restrict__ al2, const float* __restrict__ ar2,
    const float* __restrict__ Wn3, const float* __restrict__ al3, const float* __restrict__ ar3,
    const float* __restrict__ W_e2d,
    const float* __restrict__ We0, const float* __restrict__ ae0,
    const float* __restrict__ We1, const float* __restrict__ ae1,
    const float* __restrict__ We2, const float* __restrict__ ae2,
    const float* __restrict__ We3, const float* __restrict__ ae3,
    const float* __restrict__ X0,
    float* __restrict__ P4, float* __restrict__ Q, float4* __restrict__ Wpack,
    float2* __restrict__ EL2, float2* __restrict__ ER2) {
    __shared__ float praw[256];
    const int t = threadIdx.x;
    const int bb = blockIdx.x;

    if (bb < 391) {  // count
        int e = bb * 256 + t;
        if (e < N_EDGES) pos[e] = atomicAdd(&cnt[dst[e]], 1);
        return;
    }
    const int b = bb - 391;

    if (b < 4) {
        const int L = b;
        if (L != 2) {
            const float* Wn = (L == 0) ? Wn0 : (L == 1) ? Wn1 : Wn3;
            const float* al = (L == 0) ? al0 : (L == 1) ? al1 : al3;
            const float* ar = (L == 0) ? ar0 : (L == 1) ? ar1 : ar3;
            const int k = t >> 2, o = t & 3;
            const float* a = (o & 2) ? ar : al;
            const int h = o & 1;
            float acc = 0.f;
#pragma unroll 8
            for (int d = 0; d < 64; d++) acc = fmaf(Wn[k * 128 + h * 64 + d], a[h * 64 + d], acc);
            P4[L * 256 + t] = acc;
        } else {
            {
                const int i = t >> 2, o = t & 3;
                const float* a = (o & 2) ? ar2 : al2;
                const int h = o & 1;
                float acc = 0.f;
#pragma unroll 8
                for (int d = 0; d < 64; d++) acc = fmaf(dWn[i * 128 + h * 64 + d], a[h * 64 + d], acc);
                praw[t] = acc;
            }
            __syncthreads();
            const int j = t >> 2, o = t & 3;
            float acc = 0.f;
#pragma unroll 8
            for (int i = 0; i < 64; i++) acc = fmaf(W_e2d[i * 64 + j], praw[i * 4 + o], acc);
            P4[2 * 256 + t] = acc;
        }
    } else if (b == 4) {
        const int k = t >> 3, o = t & 7, L = o >> 1, h = o & 1;
        const float* We = (L == 0) ? We0 : (L == 1) ? We1 : (L == 2) ? We2 : We3;
        const float* ae = (L == 0) ? ae0 : (L == 1) ? ae1 : (L == 2) ? ae2 : ae3;
        float acc = 0.f;
#pragma unroll 8
        for (int d = 0; d < 64; d++) acc = fmaf(We[k * 128 + h * 64 + d], ae[h * 64 + d], acc);
        Q[t] = acc;
    } else if (b < 53) {
        // pack: idx in [0,12288); layer L gets 3072 float4 (2048 Wn + 1024 We)
        const int idx = (b - 5) * 256 + t;
        const int L = idx / 3072;
        const int sub = idx - L * 3072;
        if (sub < 2048) {
            const int k2 = sub >> 6, l = sub & 63;
            if (L != 2) {
                const float* Wn = (L == 0) ? Wn0 : (L == 1) ? Wn1 : Wn3;
                Wpack[idx] = make_float4(Wn[(2 * k2) * 128 + l], Wn[(2 * k2) * 128 + 64 + l],
                                         Wn[(2 * k2 + 1) * 128 + l], Wn[(2 * k2 + 1) * 128 + 64 + l]);
            } else {
                // wcomb[k][c] = sum_i W_e2d[i*64+k] * dWn[i*128+c], packed directly
                float a0 = 0.f, a1 = 0.f, a2 = 0.f, a3 = 0.f;
#pragma unroll 4
                for (int i = 0; i < 64; i++) {
                    float wa = W_e2d[i * 64 + 2 * k2], wb = W_e2d[i * 64 + 2 * k2 + 1];
                    float da = dWn[i * 128 + l], db = dWn[i * 128 + 64 + l];
                    a0 = fmaf(wa, da, a0);
                    a1 = fmaf(wa, db, a1);
                    a2 = fmaf(wb, da, a2);
                    a3 = fmaf(wb, db, a3);
                }
                Wpack[idx] = make_float4(a0, a1, a2, a3);
            }
        } else {
            const int s2 = sub - 2048;
            const int k2 = s2 >> 6, l = s2 & 63;
            const float* We = (L == 0) ? We0 : (L == 1) ? We1 : (L == 2) ? We2 : We3;
            Wpack[idx] = make_float4(We[(2 * k2) * 128 + l], We[(2 * k2) * 128 + 64 + l],
                                     We[(2 * k2 + 1) * 128 + l], We[(2 * k2 + 1) * 128 + 64 + l]);
        }
    } else {
        {
            const int k = t >> 2, o = t & 3;
            const float* a = (o & 2) ? ar0 : al0;
            const int h = o & 1;
            float acc = 0.f;
#pragma unroll 8
            for (int d = 0; d < 64; d++) acc = fmaf(Wn0[k * 128 + h * 64 + d], a[h * 64 + d], acc);
            praw[t] = acc;
        }
        __syncthreads();
        const int lane = t & 63;
        const int wave = t >> 6;
        const float px = praw[lane * 4 + 0], py = praw[lane * 4 + 1];
        const float pz = praw[lane * 4 + 2], pw = praw[lane * 4 + 3];
        const int nb = (int)gridDim.x - 444;  // blocks doing el/er
        for (int node = (b - 53) * 4 + wave; node < N_NODES; node += nb * 4) {
            float xv = X0[node * 64 + lane];
            float e0 = xv * px, e1 = xv * py, f0 = xv * pz, f1 = xv * pw;
#pragma unroll
            for (int off = 32; off; off >>= 1) {
                e0 += __shfl_xor(e0, off);
                e1 += __shfl_xor(e1, off);
                f0 += __shfl_xor(f0, off);
                f1 += __shfl_xor(f1, off);
            }
            if (lane == 0) {
                EL2[node] = make_float2(e0, e1);
                ER2[node] = make_float2(f0, f1);
            }
        }
    }
}

// ---------------------------------------------------------------------------
// prep: one pass over Efeat -> e_csr, src_csr, EE_csr (4 layers x 2 heads)
// ---------------------------------------------------------------------------
__global__ __launch_bounds__(256) void prep_kernel(const float* __restrict__ Efeat,
                                                   const int* __restrict__ src,
                                                   const int* __restrict__ dst,
                                                   const int* __restrict__ pos,
                                                   const int* __restrict__ row_ptr,
                                                   const float* __restrict__ Q,
                                                   float* __restrict__ E_csr,
                                                   int* __restrict__ src_csr,
                                                   float* __restrict__ EE_csr) {
    __shared__ float QS[256];
    __shared__ float ES[32][33];
    __shared__ int JS[32];
    const int tid = threadIdx.x;
    QS[tid] = Q[tid];
    const int e0 = blockIdx.x * 32;
    const int el_ = tid >> 3, quad = tid & 7;
    float4 v = ((const float4*)Efeat)[(size_t)(e0 + el_) * 8 + quad];
    ES[el_][quad * 4 + 0] = v.x;
    ES[el_][quad * 4 + 1] = v.y;
    ES[el_][quad * 4 + 2] = v.z;
    ES[el_][quad * 4 + 3] = v.w;
    if (tid < 32) {
        int e = e0 + tid;
        int j = row_ptr[dst[e]] + pos[e];
        JS[tid] = j;
        src_csr[j] = src[e];
    }
    __syncthreads();
    const int j = JS[el_];
    ((float4*)E_csr)[(size_t)j * 8 + quad] = v;
    const int o = quad;
    float acc = 0.f;
#pragma unroll
    for (int k = 0; k < 32; k++) acc = fmaf(ES[el_][k], QS[k * 8 + o], acc);
    EE_csr[(size_t)(o >> 1) * 2 * N_EDGES + (size_t)j * 2 + (o & 1)] = acc;
}

// ---------------------------------------------------------------------------
// gather_one — full per-node gather (deg 0 / <=64 / fallback). Used for the
// rare non-fast-path nodes in the dual-node layer kernel.
// ---------------------------------------------------------------------------
__device__ __forceinline__ void gather_one(
    int beg, int end, float2 er,
    const float* __restrict__ X, const float* __restrict__ E_csr,
    const int* __restrict__ src_csr, const float2* __restrict__ ELi,
    const float2* __restrict__ EE_L,
    int lane, int half, int hl,
    float& ax0, float& ax1, float& aeh) {
    ax0 = 0.f; ax1 = 0.f; aeh = 0.f;
    const int deg = end - beg;
    if (deg == 0) return;
    float l0 = 0.f, l1 = 0.f, aX0 = 0.f, aX1 = 0.f, aE = 0.f;
    if (deg <= 64) {
        int sn = 0;
        float w0 = 0.f, w1 = 0.f;
        if (lane < deg) {
            sn = src_csr[beg + lane];
            float2 ee = EE_L[beg + lane];
            float2 el = ELi[sn];
            w0 = __expf(lrelu(el.x + er.x + ee.x));
            w1 = __expf(lrelu(el.y + er.y + ee.y));
        }
        l0 = w0; l1 = w1;
#pragma unroll
        for (int off = 32; off; off >>= 1) {
            l0 += __shfl_xor(l0, off);
            l1 += __shfl_xor(l1, off);
        }
        const int dm1 = deg - 1;
        {
            float xs[8], es[8];
#pragma unroll
            for (int t = 0; t < 8; t++) {
                int ct = t < dm1 ? t : dm1;
                int st = rl_i(sn, ct);
                xs[t] = X[st * 64 + lane];
                es[t] = E_csr[(size_t)(beg + ct) * 32 + hl];
            }
#pragma unroll
            for (int t = 0; t < 8; t++) {
                float w0t = rl_f(w0, t);
                float w1t = rl_f(w1, t);
                aX0 = fmaf(w0t, xs[t], aX0);
                aX1 = fmaf(w1t, xs[t], aX1);
                aE = fmaf(half ? w1t : w0t, es[t], aE);
            }
        }
        int t = 8;
        for (; t + 4 <= deg; t += 4) {
            int s0 = rl_i(sn, t), s1 = rl_i(sn, t + 1);
            int s2 = rl_i(sn, t + 2), s3 = rl_i(sn, t + 3);
            float x0 = X[s0 * 64 + lane];
            float x1 = X[s1 * 64 + lane];
            float x2 = X[s2 * 64 + lane];
            float x3 = X[s3 * 64 + lane];
            const float* Eb = E_csr + (size_t)(beg + t) * 32 + hl;
            float e0 = Eb[0], e1 = Eb[32], e2 = Eb[64], e3 = Eb[96];
            float w00 = rl_f(w0, t), w01 = rl_f(w0, t + 1);
            float w02 = rl_f(w0, t + 2), w03 = rl_f(w0, t + 3);
            float w10 = rl_f(w1, t), w11 = rl_f(w1, t + 1);
            float w12 = rl_f(w1, t + 2), w13 = rl_f(w1, t + 3);
            aX0 = fmaf(w00, x0, aX0); aX1 = fmaf(w10, x0, aX1);
            aX0 = fmaf(w01, x1, aX0); aX1 = fmaf(w11, x1, aX1);
            aX0 = fmaf(w02, x2, aX0); aX1 = fmaf(w12, x2, aX1);
            aX0 = fmaf(w03, x3, aX0); aX1 = fmaf(w13, x3, aX1);
            aE = fmaf(half ? w10 : w00, e0, aE);
            aE = fmaf(half ? w11 : w01, e1, aE);
            aE = fmaf(half ? w12 : w02, e2, aE);
            aE = fmaf(half ? w13 : w03, e3, aE);
        }
        for (; t < deg; t++) {
            int st = rl_i(sn, t);
            float w0t = rl_f(w0, t), w1t = rl_f(w1, t);
            float xv = X[st * 64 + lane];
            float ev = E_csr[(size_t)(beg + t) * 32 + hl];
            aX0 = fmaf(w0t, xv, aX0);
            aX1 = fmaf(w1t, xv, aX1);
            aE = fmaf(half ? w1t : w0t, ev, aE);
        }
    } else {
        for (int c = beg; c < end; c += 64) {
            int jj = c + lane;
            int sn_ = 0;
            float w0c = 0.f, w1c = 0.f;
            if (jj < end) {
                sn_ = src_csr[jj];
                float2 ee = EE_L[jj];
                float2 el = ELi[sn_];
                w0c = __expf(lrelu(el.x + er.x + ee.x));
                w1c = __expf(lrelu(el.y + er.y + ee.y));
            }
            float s0_ = w0c, s1_ = w1c;
#pragma unroll
            for (int off = 32; off; off >>= 1) {
                s0_ += __shfl_xor(s0_, off);
                s1_ += __shfl_xor(s1_, off);
            }
            l0 += s0_;
            l1 += s1_;
            int nch = (end - c) < 64 ? (end - c) : 64;
            for (int t = 0; t < nch; t++) {
                int st = rl_i(sn_, t);
                float w0t = rl_f(w0c, t), w1t = rl_f(w1c, t);
                float xv = X[st * 64 + lane];
                float ev = E_csr[(size_t)(c + t) * 32 + hl];
                aX0 = fmaf(w0t, xv, aX0);
                aX1 = fmaf(w1t, xv, aX1);
                aE = fmaf(half ? w1t : w0t, ev, aE);
            }
        }
    }
    const float inv0 = l0 > 0.f ? 1.f / l0 : 0.f;
    const float inv1 = l1 > 0.f ? 1.f / l1 : 0.f;
    ax0 = aX0 * inv0;
    ax1 = aX1 * inv1;
    aeh = aE * (half ? inv1 : inv0);
}

// ---------------------------------------------------------------------------
// layer_kernel — FUSED gather + matmul-epilogue + next-layer el/er.
// R9 structure (empirical optimum of the session's 13-round search):
// ONE-SHOT (block churn; persistent waves pinned at ~6 waves/CU — R1-R6),
// TWO nodes per wave (ILP saturation: 1-node +32us R7, 4-node +6us R11),
// LDS-staged Wn + barrier (removing it cost +13us — R12: L1 weight reads
// lose to LDS broadcast), We from global (L1-resident, R4-neutral),
// LDS-broadcast for wave-uniform scalars (R9: VALU off critical path).
// VGPR watch: must stay <= 256 (spill = 100+ MB FETCH -> revert).
// ---------------------------------------------------------------------------
__global__ __launch_bounds__(256) void layer_kernel(
    const float* __restrict__ X,
    const float2* __restrict__ ELi, const float2* __restrict__ ERi,
    const float* __restrict__ E_csr, const int* __restrict__ src_csr,
    const int* __restrict__ row_ptr, const float2* __restrict__ EE_L,
    const float4* __restrict__ Wp, const float* __restrict__ bias,
    const float* __restrict__ P4next, const int has_next,
    float* __restrict__ OUT,
    float2* __restrict__ ELo, float2* __restrict__ ERo) {
    __shared__ float4 WS[2048];   // 32 KB: Wn-pack
    __shared__ float4 BC4[256];   //  4 KB: per-wave broadcast slab (w's, then ax's)
    __shared__ float2 AE2[256];   //  2 KB: per-wave (aeha, aehb)
    const int tid = threadIdx.x;
    const int lane = tid & 63;
    const int wave = tid >> 6;
    const int half = lane >> 5, hl = lane & 31;
    const int wb = wave * 64;     // wave-private slab base

    // ---- early issue: per-wave CSR bounds + er (independent of staging) ----
    const int n0 = blockIdx.x * 8 + wave * 2;  // 2500*8 == 20000 exactly
    const int n1 = n0 + 1;
    const int beg0 = row_ptr[n0];
    const int beg1 = row_ptr[n1];   // == end0
    const int end1 = row_ptr[n1 + 1];
    const float2 er0 = ERi[n0];
    const float2 er1 = ERi[n1];
    const float bb0 = bias[lane], bb1 = bias[64 + lane];
    const float4 p = has_next ? ((const float4*)P4next)[lane] : make_float4(0.f, 0.f, 0.f, 0.f);

#pragma unroll
    for (int i = 0; i < 8; i++) WS[i * 256 + tid] = Wp[i * 256 + tid];
    const float4* __restrict__ WeG = Wp + 2048;  // 16 KB, L1-resident
    __syncthreads();

    const int end0 = beg1;
    const int deg0 = end0 - beg0;
    const int deg1 = end1 - beg1;

    float ax0a = 0.f, ax1a = 0.f, aeha = 0.f;
    float ax0b = 0.f, ax1b = 0.f, aehb = 0.f;

    if (deg0 > 0 && deg0 <= 64 && deg1 > 0 && deg1 <= 64) {
        // ---- dual fast path: both chains interleaved ----
        int sn0 = 0, sn1 = 0;
        float w0a = 0.f, w1a = 0.f, w0b = 0.f, w1b = 0.f;
        if (lane < deg0) {
            sn0 = src_csr[beg0 + lane];
            float2 ee = EE_L[beg0 + lane];
            float2 el = ELi[sn0];
            w0a = __expf(lrelu(el.x + er0.x + ee.x));
            w1a = __expf(lrelu(el.y + er0.y + ee.y));
        }
        if (lane < deg1) {
            sn1 = src_csr[beg1 + lane];
            float2 ee = EE_L[beg1 + lane];
            float2 el = ELi[sn1];
            w0b = __expf(lrelu(el.x + er1.x + ee.x));
            w1b = __expf(lrelu(el.y + er1.y + ee.y));
        }
        // publish weights for LDS broadcast (lanes >= deg hold 0)
        BC4[wb + lane] = make_float4(w0a, w1a, w0b, w1b);
        float l0a = w0a, l1a = w1a, l0b = w0b, l1b = w1b;
#pragma unroll
        for (int off = 32; off; off >>= 1) {
            l0a += __shfl_xor(l0a, off);
            l1a += __shfl_xor(l1a, off);
            l0b += __shfl_xor(l0b, off);
            l1b += __shfl_xor(l1b, off);
        }
        float aX0a = 0.f, aX1a = 0.f, aEa = 0.f;
        float aX0b = 0.f, aX1b = 0.f, aEb = 0.f;
        const int dma = deg0 - 1, dmb = deg1 - 1;
        {
            // 32 loads in flight across both nodes
            float xs0[8], es0[8], xs1[8], es1[8];
#pragma unroll
            for (int t = 0; t < 8; t++) {
                int c0 = t < dma ? t : dma;
                int c1 = t < dmb ? t : dmb;
                int s0 = rl_i(sn0, c0);
                int s1 = rl_i(sn1, c1);
                xs0[t] = X[s0 * 64 + lane];
                es0[t] = E_csr[(size_t)(beg0 + c0) * 32 + hl];
                xs1[t] = X[s1 * 64 + lane];
                es1[t] = E_csr[(size_t)(beg1 + c1) * 32 + hl];
            }
#pragma unroll
            for (int t = 0; t < 8; t++) {
                float4 wt = BC4[wb + t];  // broadcast: 4 scalars, 1 LDS op
                aX0a = fmaf(wt.x, xs0[t], aX0a);
                aX1a = fmaf(wt.y, xs0[t], aX1a);
                aEa = fmaf(half ? wt.y : wt.x, es0[t], aEa);
                aX0b = fmaf(wt.z, xs1[t], aX0b);
                aX1b = fmaf(wt.w, xs1[t], aX1b);
                aEb = fmaf(half ? wt.w : wt.z, es1[t], aEb);
            }
        }
        // remainders (deg > 8): per node, x4 then singles
        int t = 8;
        for (; t + 4 <= deg0; t += 4) {
            int s0 = rl_i(sn0, t), s1 = rl_i(sn0, t + 1);
            int s2 = rl_i(sn0, t + 2), s3 = rl_i(sn0, t + 3);
            float x0 = X[s0 * 64 + lane];
            float x1 = X[s1 * 64 + lane];
            float x2 = X[s2 * 64 + lane];
            float x3 = X[s3 * 64 + lane];
            const float* Eb = E_csr + (size_t)(beg0 + t) * 32 + hl;
            float e0 = Eb[0], e1 = Eb[32], e2 = Eb[64], e3 = Eb[96];
            float4 wt0 = BC4[wb + t], wt1 = BC4[wb + t + 1];
            float4 wt2 = BC4[wb + t + 2], wt3 = BC4[wb + t + 3];
            aX0a = fmaf(wt0.x, x0, aX0a); aX1a = fmaf(wt0.y, x0, aX1a);
            aX0a = fmaf(wt1.x, x1, aX0a); aX1a = fmaf(wt1.y, x1, aX1a);
            aX0a = fmaf(wt2.x, x2, aX0a); aX1a = fmaf(wt2.y, x2, aX1a);
            aX0a = fmaf(wt3.x, x3, aX0a); aX1a = fmaf(wt3.y, x3, aX1a);
            aEa = fmaf(half ? wt0.y : wt0.x, e0, aEa);
            aEa = fmaf(half ? wt1.y : wt1.x, e1, aEa);
            aEa = fmaf(half ? wt2.y : wt2.x, e2, aEa);
            aEa = fmaf(half ? wt3.y : wt3.x, e3, aEa);
        }
        for (; t < deg0; t++) {
            int st = rl_i(sn0, t);
            float4 wt = BC4[wb + t];
            float xv = X[st * 64 + lane];
            float ev = E_csr[(size_t)(beg0 + t) * 32 + hl];
            aX0a = fmaf(wt.x, xv, aX0a);
            aX1a = fmaf(wt.y, xv, aX1a);
            aEa = fmaf(half ? wt.y : wt.x, ev, aEa);
        }
        t = 8;
        for (; t + 4 <= deg1; t += 4) {
            int s0 = rl_i(sn1, t), s1 = rl_i(sn1, t + 1);
            int s2 = rl_i(sn1, t + 2), s3 = rl_i(sn1, t + 3);
            float x0 = X[s0 * 64 + lane];
            float x1 = X[s1 * 64 + lane];
            float x2 = X[s2 * 64 + lane];
            float x3 = X[s3 * 64 + lane];
            const float* Eb = E_csr + (size_t)(beg1 + t) * 32 + hl;
            float e0 = Eb[0], e1 = Eb[32], e2 = Eb[64], e3 = Eb[96];
            float4 wt0 = BC4[wb + t], wt1 = BC4[wb + t + 1];
            float4 wt2 = BC4[wb + t + 2], wt3 = BC4[wb + t + 3];
            aX0b = fmaf(wt0.z, x0, aX0b); aX1b = fmaf(wt0.w, x0, aX1b);
            aX0b = fmaf(wt1.z, x1, aX0b); aX1b = fmaf(wt1.w, x1, aX1b);
            aX0b = fmaf(wt2.z, x2, aX0b); aX1b = fmaf(wt2.w, x2, aX1b);
            aX0b = fmaf(wt3.z, x3, aX0b); aX1b = fmaf(wt3.w, x3, aX1b);
            aEb = fmaf(half ? wt0.w : wt0.z, e0, aEb);
            aEb = fmaf(half ? wt1.w : wt1.z, e1, aEb);
            aEb = fmaf(half ? wt2.w : wt2.z, e2, aEb);
            aEb = fmaf(half ? wt3.w : wt3.z, e3, aEb);
        }
        for (; t < deg1; t++) {
            int st = rl_i(sn1, t);
            float4 wt = BC4[wb + t];
            float xv = X[st * 64 + lane];
            float ev = E_csr[(size_t)(beg1 + t) * 32 + hl];
            aX0b = fmaf(wt.z, xv, aX0b);
            aX1b = fmaf(wt.w, xv, aX1b);
            aEb = fmaf(half ? wt.w : wt.z, ev, aEb);
        }
        const float i0a = l0a > 0.f ? 1.f / l0a : 0.f;
        const float i1a = l1a > 0.f ? 1.f / l1a : 0.f;
        const float i0b = l0b > 0.f ? 1.f / l0b : 0.f;
        const float i1b = l1b > 0.f ? 1.f / l1b : 0.f;
        ax0a = aX0a * i0a; ax1a = aX1a * i1a; aeha = aEa * (half ? i1a : i0a);
        ax0b = aX0b * i0b; ax1b = aX1b * i1b; aehb = aEb * (half ? i1b : i0b);
    } else {
        // rare path (deg==0 or deg>64 on either node): sequential full gather
        gather_one(beg0, end0, er0, X, E_csr, src_csr, ELi, EE_L, lane, half, hl,
                   ax0a, ax1a, aeha);
        gather_one(beg1, end1, er1, X, E_csr, src_csr, ELi, EE_L, lane, half, hl,
                   ax0b, ax1b, aehb);
    }

    // --- publish aggregates for the broadcast epilogue (reuse BC4 slab) ---
    BC4[wb + lane] = make_float4(ax0a, ax1a, ax0b, ax1b);
    AE2[wb + lane] = make_float2(aeha, aehb);

    // --- fused 2-node epilogue: Wn from LDS, aggregates via LDS broadcast ---
    float r0a = 0.f, r1a = 0.f, r0b = 0.f, r1b = 0.f;
#pragma unroll
    for (int k2 = 0; k2 < 32; k2++) {
        float4 w4 = WS[k2 * 64 + lane];
        float4 a0 = BC4[wb + 2 * k2];      // (ax0a,ax1a,ax0b,ax1b)[2k2]
        float4 a1 = BC4[wb + 2 * k2 + 1];  // same at 2k2+1
        r0a = fmaf(a0.x, w4.x, r0a); r1a = fmaf(a0.y, w4.y, r1a);
        r0a = fmaf(a1.x, w4.z, r0a); r1a = fmaf(a1.y, w4.w, r1a);
        r0b = fmaf(a0.z, w4.x, r0b); r1b = fmaf(a0.w, w4.y, r1b);
        r0b = fmaf(a1.z, w4.z, r0b); r1b = fmaf(a1.w, w4.w, r1b);
    }
#pragma unroll
    for (int k2 = 0; k2 < 16; k2++) {
        float4 w4 = WeG[k2 * 64 + lane];
        float2 e0 = AE2[wb + 2 * k2];
        float2 e1 = AE2[wb + 2 * k2 + 1];
        float2 e2 = AE2[wb + 32 + 2 * k2];
        float2 e3 = AE2[wb + 32 + 2 * k2 + 1];
        r0a = fmaf(e0.x, w4.x, r0a); r1a = fmaf(e2.x, w4.y, r1a);
        r0a = fmaf(e1.x, w4.z, r0a); r1a = fmaf(e3.x, w4.w, r1a);
        r0b = fmaf(e0.y, w4.x, r0b); r1b = fmaf(e2.y, w4.y, r1b);
        r0b = fmaf(e1.y, w4.z, r0b); r1b = fmaf(e3.y, w4.w, r1b);
    }
    const float outa = 0.5f * (r0a + bb0 + r1a + bb1);
    const float outb = 0.5f * (r0b + bb0 + r1b + bb1);
    OUT[n0 * 64 + lane] = outa;
    OUT[n1 * 64 + lane] = outb;
    if (has_next) {
        float e0a = outa * p.x, e1a = outa * p.y, f0a = outa * p.z, f1a = outa * p.w;
        float e0b = outb * p.x, e1b = outb * p.y, f0b = outb * p.z, f1b = outb * p.w;
#pragma unroll
        for (int off = 32; off; off >>= 1) {
            e0a += __shfl_xor(e0a, off); e1a += __shfl_xor(e1a, off);
            f0a += __shfl_xor(f0a, off); f1a += __shfl_xor(f1a, off);
            e0b += __shfl_xor(e0b, off); e1b += __shfl_xor(e1b, off);
            f0b += __shfl_xor(f0b, off); f1b += __shfl_xor(f1b, off);
        }
        if (lane == 0) {
            ELo[n0] = make_float2(e0a, e1a);
            ERo[n0] = make_float2(f0a, f1a);
            ELo[n1] = make_float2(e0b, e1b);
            ERo[n1] = make_float2(f0b, f1b);
        }
    }
}

// ---------------------------------------------------------------------------
extern "C" void kernel_launch(void* const* d_in, const int* in_sizes, int n_in,
                              void* d_out, int out_size, void* d_ws, size_t ws_size,
                              hipStream_t stream) {
    const float* x = (const float*)d_in[0];
    const float* e = (const float*)d_in[1];
    const int* src = (const int*)d_in[2];
    const int* dst = (const int*)d_in[3];

    // Only the LAST snapshot contributes to the output (decoded[-1]).
    const float* x1 = x + (size_t)1 * N_NODES * 64;
    const float* e1 = e + (size_t)1 * N_EDGES * 32;
    const int* src1 = src + N_EDGES;
    const int* dst1 = dst + N_EDGES;

    int we2d_idx, dec0_b, dec1_b;
    if (in_sizes[16] == 64 * 64 && in_sizes[17] == 64 * 128) {
        we2d_idx = 16; dec0_b = 17; dec1_b = 23;
    } else {
        dec0_b = 16; dec1_b = 22; we2d_idx = 28;
    }
    auto P = [&](int i) { return (const float*)d_in[i]; };

    // workspace layout (bytes)
    char* ws = (char*)d_ws;
    int* cnt      = (int*)(ws + 0);          //     80,000
    int* row_ptr  = (int*)(ws + 80000);      //     80,004
    int* pos      = (int*)(ws + 160064);     //    400,000
    float* q      = (float*)(ws + 560576);   //      1,024
    int* src_csr  = (int*)(ws + 561600);     //    400,000
    float* e_csr  = (float*)(ws + 961600);   // 12,800,000
    float* ee_csr = (float*)(ws + 13761600); //  3,200,000
    float* p4_all = (float*)(ws + 16961600); //      4,096
    float* elA    = (float*)(ws + 16965696); //    160,000
    float* erA    = (float*)(ws + 17125696); //    160,000
    float* elB    = (float*)(ws + 17285696); //    160,000
    float* erB    = (float*)(ws + 17445696); //    160,000
    float* h0     = (float*)(ws + 17605696); //  5,120,000
    float* h1     = (float*)(ws + 22725696); //  5,120,000
    float4* wpack = (float4*)(ws + 27845696);//    196,608
    // total ~28.1 MB

    hipMemsetAsync(cnt, 0, N_NODES * sizeof(int), stream);

    // merged count + params: 391 count blocks + 512 param blocks
    setup_kernel<<<903, 256, 0, stream>>>(
        dst1, cnt, pos,
        P(4), P(6), P(7),
        P(10), P(12), P(13),
        P(dec0_b + 0), P(dec0_b + 2), P(dec0_b + 3),
        P(dec1_b + 0), P(dec1_b + 2), P(dec1_b + 3),
        P(we2d_idx),
        P(5), P(8), P(11), P(14),
        P(dec0_b + 1), P(dec0_b + 4), P(dec1_b + 1), P(dec1_b + 4),
        x1,
        p4_all, q, wpack, (float2*)elA, (float2*)erA);

    const int SB = (N_NODES + 255) / 256;  // 79
    scan_kernel<<<SB, 256, 0, stream>>>(cnt, row_ptr);

    prep_kernel<<<N_EDGES / 32, 256, 0, stream>>>(e1, src1, dst1, pos, row_ptr, q,
                                                  e_csr, src_csr, ee_csr);

    // fused layer kernels: ONE-SHOT, 2500 blocks x 256 thr, 2 nodes/wave
    const int NB_L = N_NODES / 8;  // 2500
    auto run = [&](const float* Xin, int L, const float* bias_,
                   const float* elI, const float* erI,
                   float* Out, float* elO, float* erO, int hn) {
        layer_kernel<<<NB_L, 256, 0, stream>>>(
            Xin, (const float2*)elI, (const float2*)erI,
            e_csr, src_csr, row_ptr,
            (const float2*)ee_csr + (size_t)L * N_EDGES,
            wpack + (size_t)L * 3072, bias_,
            p4_all + (L + 1) * 256, hn,
            Out, (float2*)elO, (float2*)erO);
    };

    run(x1, 0, P(9),           elA, erA, h0, elB, erB, 1);
    run(h0, 1, P(15),          elB, erB, h1, elA, erA, 1);
    run(h1, 2, P(dec0_b + 5),  elA, erA, h0, elB, erB, 1);
    run(h0, 3, P(dec1_b + 5),  elB, erB, (float*)d_out, elA, erA, 0);
}